// Round 4
// baseline (438.621 us; speedup 1.0000x reference)
//
#include <hip/hip_runtime.h>
#include <hip/hip_bf16.h>

// GRU-like fused cell: out = (1-z)*tanh(i_n + r*h_n) + z*e
// B=8, H=512, N=8192. bf16 MFMA 16x16x32, fp32 acc, fused epilogue.
//
// R3 -> R4: R3 fixed scratch spill (WRITE 1.38GB->132MB) but VALUBusy 23% with
// only ~120 source VALU/step => register-allocator AGPR<->VGPR shuffling
// (demand ~230 vs 124 arch VGPRs). Surgery: halve X staging to 16 transient
// regs, precompute LDS read offsets (immediates for gate/mi/ni), pad buffer
// stride to 64KB so parity is one bit. VGPR-side demand ~95 -> clean allocation.

#define HH 512
#define NBATCH 8
#define NN 8192
#define BN 256
#define BK 64
#define NSTEPS 16
#define THREADS 512
#define A_BYTES (192 * BK * 2)          // 24576
#define B_BYTES (BN * BK * 2)           // 32768
#define BUF_STRIDE 65536                // pow2 pad: buffer parity = one high bit
#define LDS_TOTAL (BUF_STRIDE + A_BYTES + B_BYTES)   // 122880 <= 160K

typedef __attribute__((ext_vector_type(8))) short short8;
typedef __attribute__((ext_vector_type(4))) float f32x4;

__device__ __forceinline__ unsigned cvt_pk_bf16(float a, float b) {
  unsigned r;
  asm("v_cvt_pk_bf16_f32 %0, %1, %2" : "=v"(r) : "v"(a), "v"(b));
  return r;
}

__device__ __forceinline__ void gload_lds16(const void* g, void* l) {
  __builtin_amdgcn_global_load_lds(
      (__attribute__((address_space(1))) void*)(g),
      (__attribute__((address_space(3))) void*)(l), 16, 0, 0);
}

#define MFMA16(a_, b_, c_) __builtin_amdgcn_mfma_f32_16x16x32_bf16((a_), (b_), (c_), 0, 0, 0)

// ---------------- weight pre-pack (unchanged, verified R1-R3) ----------------
__global__ void prepack_w(const float* __restrict__ W_ih, const float* __restrict__ W_hh,
                          __hip_bfloat16* __restrict__ ws) {
  int t = blockIdx.x * 256 + threadIdx.x;
  int blk = t / 12288;                              // ht*16 + s
  int e = t % 12288;
  int ra = e >> 6;                                  // 0..191
  int kk = (e & 63) ^ ((ra & 7) << 3);              // inverse of read-side XOR swizzle
  int gate = ra >> 6;
  int h = (blk >> 4) * 64 + (ra & 63);
  int row = gate * HH + h;
  int kg = (blk & 15) * 64 + kk;
  float v = (kg < 512) ? W_ih[row * 512 + kg] : W_hh[row * 512 + (kg - 512)];
  ws[t] = __float2bfloat16(v);
}

// ---------------- main fused kernel ----------------
__global__ __launch_bounds__(THREADS, 2)
void gru_main(const float* __restrict__ e_wv, const float* __restrict__ m_wv,
              const __hip_bfloat16* __restrict__ wimg, float* __restrict__ out) {
  extern __shared__ char smem[];
  const int tid  = threadIdx.x;
  const int lane = tid & 63;
  const int wave = tid >> 6;
  const int wm = wave >> 2;        // 0..1 : 32-row half of 64-h tile
  const int wn = wave & 3;         // 0..3 : 64-col quarter of 256-n tile

  const int wg  = blockIdx.x;
  const int swz = (wg & 7) * 256 + (wg >> 3);
  const int ht  = swz & 7;
  const int nt  = (swz >> 3) & 31;
  const int b   = swz >> 8;

  const int k0  = (tid & 15) << 2;   // 0..60  (4 k-rows per thread)
  const int n0s = (tid >> 4) << 3;   // 0..248 (8 n-cols per thread)

  const size_t batch_off = (size_t)b * HH * NN;
  const float* xm = m_wv + batch_off + (size_t)k0 * NN + nt * BN + n0s;
  const float* xe = e_wv + batch_off + (size_t)k0 * NN + nt * BN + n0s;
  const char*  wA = (const char*)wimg + (size_t)ht * NSTEPS * A_BYTES + tid * 16;

  f32x4 acc_r[2][4]  = {};
  f32x4 acc_z[2][4]  = {};
  f32x4 acc_in[2][4] = {};
  f32x4 acc_hn[2][4] = {};

  // Precomputed within-buffer LDS read offsets. Row&7 == lane&7 for both A and B
  // reads, so the XOR swizzle term is lane-fixed; gate/mi/ni strides are imms.
  int aoff[2], boff[2];
#pragma unroll
  for (int kb2 = 0; kb2 < 2; ++kb2) {
    const int ke2 = kb2 * 64 + ((lane >> 4) << 4);
    const int sw  = (lane & 7) << 4;
    aoff[kb2] = (wm * 32 + (lane & 15)) * 128 + (ke2 ^ sw);
    boff[kb2] = A_BYTES + (wn * 64 + (lane & 15)) * 128 + (ke2 ^ sw);
  }

  auto issue_A = [&](int s, char* nb) {
    const char* gA = wA + (size_t)s * A_BYTES;
    char* lA = nb + tid * 16;
    gload_lds16(gA,         lA);
    gload_lds16(gA + 8192,  lA + 8192);
    gload_lds16(gA + 16384, lA + 16384);
  };
  auto x_load_half = [&](const float* xs, int h, f32x4 c[4]) {
#pragma unroll
    for (int i = 0; i < 4; ++i) c[i] = *(const f32x4*)(xs + (size_t)i * NN + h * 4);
  };
  auto x_write_half = [&](char* nb, int h, const f32x4 c[4]) {
    char* Bb = nb + A_BYTES;
#pragma unroll
    for (int j2 = 0; j2 < 4; ++j2) {
      const int j = h * 4 + j2;
      unsigned lo = cvt_pk_bf16(c[0][j2], c[1][j2]);
      unsigned hi = cvt_pk_bf16(c[2][j2], c[3][j2]);
      int off = (n0s + j) * 128 + ((k0 * 2) ^ (j << 4));   // (n&7)==j
      *(uint2*)(Bb + off) = make_uint2(lo, hi);
    }
  };
  auto compute_kb2 = [&](const char* cb, int kb2, bool firstHalf) {
    short8 bfr[4];
#pragma unroll
    for (int ni = 0; ni < 4; ++ni)
      bfr[ni] = *(const short8*)(cb + boff[kb2] + ni * 2048);
    // gate r
    {
      short8 a0 = *(const short8*)(cb + aoff[kb2]);
      short8 a1 = *(const short8*)(cb + aoff[kb2] + 2048);
#pragma unroll
      for (int ni = 0; ni < 4; ++ni) {
        acc_r[0][ni] = MFMA16(a0, bfr[ni], acc_r[0][ni]);
        acc_r[1][ni] = MFMA16(a1, bfr[ni], acc_r[1][ni]);
      }
    }
    // gate z
    {
      short8 a0 = *(const short8*)(cb + aoff[kb2] + 8192);
      short8 a1 = *(const short8*)(cb + aoff[kb2] + 8192 + 2048);
#pragma unroll
      for (int ni = 0; ni < 4; ++ni) {
        acc_z[0][ni] = MFMA16(a0, bfr[ni], acc_z[0][ni]);
        acc_z[1][ni] = MFMA16(a1, bfr[ni], acc_z[1][ni]);
      }
    }
    // gate n -> acc_in (m-phase) / acc_hn (e-phase)
    {
      short8 a0 = *(const short8*)(cb + aoff[kb2] + 16384);
      short8 a1 = *(const short8*)(cb + aoff[kb2] + 16384 + 2048);
      if (firstHalf) {
#pragma unroll
        for (int ni = 0; ni < 4; ++ni) {
          acc_in[0][ni] = MFMA16(a0, bfr[ni], acc_in[0][ni]);
          acc_in[1][ni] = MFMA16(a1, bfr[ni], acc_in[1][ni]);
        }
      } else {
#pragma unroll
        for (int ni = 0; ni < 4; ++ni) {
          acc_hn[0][ni] = MFMA16(a0, bfr[ni], acc_hn[0][ni]);
          acc_hn[1][ni] = MFMA16(a1, bfr[ni], acc_hn[1][ni]);
        }
      }
    }
  };

  // prologue: stage step 0 into buf0
  issue_A(0, smem);
  {
    f32x4 c[4];
    x_load_half(xm, 0, c);
    x_write_half(smem, 0, c);
    x_load_half(xm, 1, c);
    x_write_half(smem, 1, c);
  }
  __syncthreads();

#pragma unroll 1
  for (int s = 0; s < NSTEPS; ++s) {
    char* cb = smem + ((s & 1) ? BUF_STRIDE : 0);
    char* nb = smem + ((s & 1) ? 0 : BUF_STRIDE);
    const bool pre = (s < NSTEPS - 1);
    const bool firstHalf = (s < 8);
    const float* xs = (s + 1 < 8 ? xm : xe) + (size_t)((s + 1) & 7) * (64 * NN);

    if (pre) issue_A(s + 1, nb);
    f32x4 c[4];
    if (pre) x_load_half(xs, 0, c);        // in flight under kb2=0 compute
    compute_kb2(cb, 0, firstHalf);
    if (pre) { x_write_half(nb, 0, c); x_load_half(xs, 1, c); }
    compute_kb2(cb, 1, firstHalf);
    if (pre) x_write_half(nb, 1, c);
    __syncthreads();
  }

  // epilogue: gates + blend (unchanged, verified R1-R3)
  const size_t obase = batch_off + (size_t)(ht * 64 + wm * 32) * NN + nt * BN + wn * 64;
  const float* ep = e_wv + obase;
  float* op = out + obase;
  const int rsub = (lane >> 4) << 2;
  const int csub = lane & 15;
#pragma unroll
  for (int mi = 0; mi < 2; ++mi)
#pragma unroll
    for (int ni = 0; ni < 4; ++ni) {
#pragma unroll
      for (int r = 0; r < 4; ++r) {
        size_t idx = (size_t)(mi * 16 + rsub + r) * NN + ni * 16 + csub;
        float pr  = acc_r[mi][ni][r];
        float pz  = acc_z[mi][ni][r];
        float vin = acc_in[mi][ni][r];
        float vhn = acc_hn[mi][ni][r];
        float rr  = 1.f / (1.f + __expf(-pr));
        float zz  = 1.f / (1.f + __expf(-pz));
        float ex  = __expf(2.f * (vin + rr * vhn));
        float nn2 = 1.f - 2.f / (ex + 1.f);      // tanh, inf-safe
        float ev  = ep[idx];
        op[idx] = (1.f - zz) * nn2 + zz * ev;
      }
    }
}

extern "C" void kernel_launch(void* const* d_in, const int* in_sizes, int n_in,
                              void* d_out, int out_size, void* d_ws, size_t ws_size,
                              hipStream_t stream) {
  const float* e_wv = (const float*)d_in[0];
  const float* m_wv = (const float*)d_in[1];
  const float* W_ih = (const float*)d_in[2];
  const float* W_hh = (const float*)d_in[3];
  float* out = (float*)d_out;
  __hip_bfloat16* wimg = (__hip_bfloat16*)d_ws;   // 3 MiB weight image

  (void)hipFuncSetAttribute((const void*)gru_main,
                            hipFuncAttributeMaxDynamicSharedMemorySize, LDS_TOTAL);

  prepack_w<<<(NBATCH * NSTEPS * 12288) / 256, 256, 0, stream>>>(W_ih, W_hh, wimg);
  gru_main<<<NBATCH * 8 * 32, THREADS, LDS_TOTAL, stream>>>(e_wv, m_wv, wimg, out);
}

// Round 5
// 384.990 us; speedup vs baseline: 1.1393x; 1.1393x over previous
//
#include <hip/hip_runtime.h>
#include <hip/hip_bf16.h>

// GRU-like fused cell: out = (1-z)*tanh(i_n + r*h_n) + z*e
// B=8, H=512, N=8192. bf16 MFMA 16x16x32, fp32 acc, fused epilogue.
//
// R4 -> R5: R4 showed the limiter is NOT registers (R3==R4): 9.2k cyc/step vs
// ~470 cyc of MFMA -- single 512-thr WG/CU = one barrier domain, 2 lockstep
// waves/SIMD, X-load latency exposed at every vmcnt/barrier with zero overlap.
// Fix: 256-thr WGs (64h x 128n), LDS 81920/WG => exactly 2 WGs/CU, independent
// barrier domains; each SIMD gets one wave from each WG -> stalls of one WG
// hide under MFMA of the other. Inner loop per wave unchanged.

#define HH 512
#define NBATCH 8
#define NN 8192
#define BN 128
#define BK 64
#define NSTEPS 16
#define THREADS 256
#define A_BYTES (192 * BK * 2)          // 24576
#define B_BYTES (BN * BK * 2)           // 16384
#define BUF_BYTES (A_BYTES + B_BYTES)   // 40960
#define LDS_TOTAL (2 * BUF_BYTES)       // 81920 -> 2 WGs/CU (2x = 163840 = full LDS)

typedef __attribute__((ext_vector_type(8))) short short8;
typedef __attribute__((ext_vector_type(4))) float f32x4;

__device__ __forceinline__ unsigned cvt_pk_bf16(float a, float b) {
  unsigned r;
  asm("v_cvt_pk_bf16_f32 %0, %1, %2" : "=v"(r) : "v"(a), "v"(b));
  return r;
}

__device__ __forceinline__ void gload_lds16(const void* g, void* l) {
  __builtin_amdgcn_global_load_lds(
      (__attribute__((address_space(1))) void*)(g),
      (__attribute__((address_space(3))) void*)(l), 16, 0, 0);
}

#define MFMA16(a_, b_, c_) __builtin_amdgcn_mfma_f32_16x16x32_bf16((a_), (b_), (c_), 0, 0, 0)

// ---------------- weight pre-pack (unchanged, verified R1-R4) ----------------
// blocks of 192x64 bf16 per (ht, s), row-major 128B rows, XOR-swizzled.
__global__ void prepack_w(const float* __restrict__ W_ih, const float* __restrict__ W_hh,
                          __hip_bfloat16* __restrict__ ws) {
  int t = blockIdx.x * 256 + threadIdx.x;
  int blk = t / 12288;                              // ht*16 + s
  int e = t % 12288;
  int ra = e >> 6;                                  // 0..191
  int kk = (e & 63) ^ ((ra & 7) << 3);              // inverse of read-side XOR swizzle
  int gate = ra >> 6;
  int h = (blk >> 4) * 64 + (ra & 63);
  int row = gate * HH + h;
  int kg = (blk & 15) * 64 + kk;
  float v = (kg < 512) ? W_ih[row * 512 + kg] : W_hh[row * 512 + (kg - 512)];
  ws[t] = __float2bfloat16(v);
}

// ---------------- main fused kernel ----------------
__global__ __launch_bounds__(THREADS, 2)
void gru_main(const float* __restrict__ e_wv, const float* __restrict__ m_wv,
              const __hip_bfloat16* __restrict__ wimg, float* __restrict__ out) {
  extern __shared__ char smem[];
  const int tid  = threadIdx.x;
  const int lane = tid & 63;
  const int wave = tid >> 6;       // 0..3
  const int wm = wave >> 1;        // 0..1 : 32-row half of 64-h tile
  const int wn = wave & 1;         // 0..1 : 64-col half of 128-n tile

  // XCD swizzle (bijective: 4096 % 8 == 0), ht fastest within an XCD so the
  // 8 ht-sharers of one X slab run concurrently on the same XCD's L2.
  const int wg  = blockIdx.x;
  const int swz = (wg & 7) * 512 + (wg >> 3);
  const int ht  = swz & 7;
  const int nt  = (swz >> 3) & 63;
  const int b   = swz >> 9;

  const int k0  = (tid & 15) << 2;   // 0..60  (4 k-rows per thread)
  const int n0s = (tid >> 4) << 3;   // 0..120 (8 n-cols per thread)

  const size_t batch_off = (size_t)b * HH * NN;
  const float* xm = m_wv + batch_off + (size_t)k0 * NN + nt * BN + n0s;
  const float* xe = e_wv + batch_off + (size_t)k0 * NN + nt * BN + n0s;
  const char*  wA = (const char*)wimg + (size_t)ht * NSTEPS * A_BYTES + tid * 16;

  f32x4 acc_r[2][4]  = {};
  f32x4 acc_z[2][4]  = {};
  f32x4 acc_in[2][4] = {};
  f32x4 acc_hn[2][4] = {};

  // Precomputed within-buffer LDS read offsets (swizzle term lane-fixed;
  // gate/mi/ni strides are immediates).
  int aoff[2], boff[2];
#pragma unroll
  for (int kb2 = 0; kb2 < 2; ++kb2) {
    const int ke2 = kb2 * 64 + ((lane >> 4) << 4);
    const int sw  = (lane & 7) << 4;
    aoff[kb2] = (wm * 32 + (lane & 15)) * 128 + (ke2 ^ sw);
    boff[kb2] = A_BYTES + (wn * 64 + (lane & 15)) * 128 + (ke2 ^ sw);
  }

  auto issue_A = [&](int s, char* nb) {
    const char* gA = wA + (size_t)s * A_BYTES;
    char* lA = nb + tid * 16;
#pragma unroll
    for (int i = 0; i < 6; ++i)
      gload_lds16(gA + i * 4096, lA + i * 4096);
  };
  auto x_load_half = [&](const float* xs, int h, f32x4 c[4]) {
#pragma unroll
    for (int i = 0; i < 4; ++i) c[i] = *(const f32x4*)(xs + (size_t)i * NN + h * 4);
  };
  auto x_write_half = [&](char* nb, int h, const f32x4 c[4]) {
    char* Bb = nb + A_BYTES;
#pragma unroll
    for (int j2 = 0; j2 < 4; ++j2) {
      const int j = h * 4 + j2;
      unsigned lo = cvt_pk_bf16(c[0][j2], c[1][j2]);
      unsigned hi = cvt_pk_bf16(c[2][j2], c[3][j2]);
      int off = (n0s + j) * 128 + ((k0 * 2) ^ (j << 4));   // (n&7)==j
      *(uint2*)(Bb + off) = make_uint2(lo, hi);
    }
  };
  auto compute_kb2 = [&](const char* cb, int kb2, bool firstHalf) {
    short8 bfr[4];
#pragma unroll
    for (int ni = 0; ni < 4; ++ni)
      bfr[ni] = *(const short8*)(cb + boff[kb2] + ni * 2048);
    {  // gate r
      short8 a0 = *(const short8*)(cb + aoff[kb2]);
      short8 a1 = *(const short8*)(cb + aoff[kb2] + 2048);
#pragma unroll
      for (int ni = 0; ni < 4; ++ni) {
        acc_r[0][ni] = MFMA16(a0, bfr[ni], acc_r[0][ni]);
        acc_r[1][ni] = MFMA16(a1, bfr[ni], acc_r[1][ni]);
      }
    }
    {  // gate z
      short8 a0 = *(const short8*)(cb + aoff[kb2] + 8192);
      short8 a1 = *(const short8*)(cb + aoff[kb2] + 8192 + 2048);
#pragma unroll
      for (int ni = 0; ni < 4; ++ni) {
        acc_z[0][ni] = MFMA16(a0, bfr[ni], acc_z[0][ni]);
        acc_z[1][ni] = MFMA16(a1, bfr[ni], acc_z[1][ni]);
      }
    }
    {  // gate n -> acc_in (m-phase) / acc_hn (e-phase)
      short8 a0 = *(const short8*)(cb + aoff[kb2] + 16384);
      short8 a1 = *(const short8*)(cb + aoff[kb2] + 16384 + 2048);
      if (firstHalf) {
#pragma unroll
        for (int ni = 0; ni < 4; ++ni) {
          acc_in[0][ni] = MFMA16(a0, bfr[ni], acc_in[0][ni]);
          acc_in[1][ni] = MFMA16(a1, bfr[ni], acc_in[1][ni]);
        }
      } else {
#pragma unroll
        for (int ni = 0; ni < 4; ++ni) {
          acc_hn[0][ni] = MFMA16(a0, bfr[ni], acc_hn[0][ni]);
          acc_hn[1][ni] = MFMA16(a1, bfr[ni], acc_hn[1][ni]);
        }
      }
    }
  };

  // prologue: stage step 0 into buf0
  issue_A(0, smem);
  {
    f32x4 c[4];
    x_load_half(xm, 0, c);
    x_write_half(smem, 0, c);
    x_load_half(xm, 1, c);
    x_write_half(smem, 1, c);
  }
  __syncthreads();

#pragma unroll 1
  for (int s = 0; s < NSTEPS; ++s) {
    char* cb = smem + ((s & 1) ? BUF_BYTES : 0);
    char* nb = smem + ((s & 1) ? 0 : BUF_BYTES);
    const bool pre = (s < NSTEPS - 1);
    const bool firstHalf = (s < 8);
    const float* xs = (s + 1 < 8 ? xm : xe) + (size_t)((s + 1) & 7) * (64 * NN);

    f32x4 c[4];
    if (pre) x_load_half(xs, 0, c);        // issue early: in flight under kb2=0
    if (pre) issue_A(s + 1, nb);
    compute_kb2(cb, 0, firstHalf);
    if (pre) { x_write_half(nb, 0, c); x_load_half(xs, 1, c); }
    compute_kb2(cb, 1, firstHalf);
    if (pre) x_write_half(nb, 1, c);
    __syncthreads();
  }

  // epilogue: gates + blend (unchanged, verified R1-R4)
  const size_t obase = batch_off + (size_t)(ht * 64 + wm * 32) * NN + nt * BN + wn * 64;
  const float* ep = e_wv + obase;
  float* op = out + obase;
  const int rsub = (lane >> 4) << 2;
  const int csub = lane & 15;
#pragma unroll
  for (int mi = 0; mi < 2; ++mi)
#pragma unroll
    for (int ni = 0; ni < 4; ++ni) {
#pragma unroll
      for (int r = 0; r < 4; ++r) {
        size_t idx = (size_t)(mi * 16 + rsub + r) * NN + ni * 16 + csub;
        float pr  = acc_r[mi][ni][r];
        float pz  = acc_z[mi][ni][r];
        float vin = acc_in[mi][ni][r];
        float vhn = acc_hn[mi][ni][r];
        float rr  = 1.f / (1.f + __expf(-pr));
        float zz  = 1.f / (1.f + __expf(-pz));
        float ex  = __expf(2.f * (vin + rr * vhn));
        float nn2 = 1.f - 2.f / (ex + 1.f);      // tanh, inf-safe
        float ev  = ep[idx];
        op[idx] = (1.f - zz) * nn2 + zz * ev;
      }
    }
}

extern "C" void kernel_launch(void* const* d_in, const int* in_sizes, int n_in,
                              void* d_out, int out_size, void* d_ws, size_t ws_size,
                              hipStream_t stream) {
  const float* e_wv = (const float*)d_in[0];
  const float* m_wv = (const float*)d_in[1];
  const float* W_ih = (const float*)d_in[2];
  const float* W_hh = (const float*)d_in[3];
  float* out = (float*)d_out;
  __hip_bfloat16* wimg = (__hip_bfloat16*)d_ws;   // 3 MiB weight image

  (void)hipFuncSetAttribute((const void*)gru_main,
                            hipFuncAttributeMaxDynamicSharedMemorySize, LDS_TOTAL);

  prepack_w<<<(NBATCH * NSTEPS * 12288) / 256, 256, 0, stream>>>(W_ih, W_hh, wimg);
  gru_main<<<NBATCH * 8 * 64, THREADS, LDS_TOTAL, stream>>>(e_wv, m_wv, wimg, out);
}

// Round 6
// 373.126 us; speedup vs baseline: 1.1755x; 1.0318x over previous
//
#include <hip/hip_runtime.h>
#include <hip/hip_bf16.h>

// GRU-like fused cell: out = (1-z)*tanh(i_n + r*h_n) + z*e
// B=8, H=512, N=8192. bf16 MFMA 16x16x32, fp32 acc, fused epilogue.
//
// R5 -> R6: R5 (2 WGs/CU) still 8000 cyc/step vs ~460 cyc MFMA: X loads were
// consumed ~250 cyc after issue -> 2 vmcnt stalls/step of ~1-2k cyc each.
// Now X pipeline depth 2: write X(s+1) from packed regs at step top (no wait),
// issue X(s+2) loads, compute (full step of latency cover), convert f32->bf16
// at step end. Cross-barrier live set = 16 packed VGPRs. + setprio around MFMA.

#define HH 512
#define NBATCH 8
#define NN 8192
#define BN 128
#define BK 64
#define NSTEPS 16
#define THREADS 256
#define A_BYTES (192 * BK * 2)          // 24576
#define B_BYTES (BN * BK * 2)           // 16384
#define BUF_BYTES (A_BYTES + B_BYTES)   // 40960
#define LDS_TOTAL (2 * BUF_BYTES)       // 81920 -> 2 WGs/CU

typedef __attribute__((ext_vector_type(8))) short short8;
typedef __attribute__((ext_vector_type(4))) float f32x4;

__device__ __forceinline__ unsigned cvt_pk_bf16(float a, float b) {
  unsigned r;
  asm("v_cvt_pk_bf16_f32 %0, %1, %2" : "=v"(r) : "v"(a), "v"(b));
  return r;
}

__device__ __forceinline__ void gload_lds16(const void* g, void* l) {
  __builtin_amdgcn_global_load_lds(
      (__attribute__((address_space(1))) void*)(g),
      (__attribute__((address_space(3))) void*)(l), 16, 0, 0);
}

#define MFMA16(a_, b_, c_) __builtin_amdgcn_mfma_f32_16x16x32_bf16((a_), (b_), (c_), 0, 0, 0)

// ---------------- weight pre-pack (unchanged, verified R1-R5) ----------------
__global__ void prepack_w(const float* __restrict__ W_ih, const float* __restrict__ W_hh,
                          __hip_bfloat16* __restrict__ ws) {
  int t = blockIdx.x * 256 + threadIdx.x;
  int blk = t / 12288;                              // ht*16 + s
  int e = t % 12288;
  int ra = e >> 6;                                  // 0..191
  int kk = (e & 63) ^ ((ra & 7) << 3);              // inverse of read-side XOR swizzle
  int gate = ra >> 6;
  int h = (blk >> 4) * 64 + (ra & 63);
  int row = gate * HH + h;
  int kg = (blk & 15) * 64 + kk;
  float v = (kg < 512) ? W_ih[row * 512 + kg] : W_hh[row * 512 + (kg - 512)];
  ws[t] = __float2bfloat16(v);
}

// ---------------- main fused kernel ----------------
__global__ __launch_bounds__(THREADS, 2)
void gru_main(const float* __restrict__ e_wv, const float* __restrict__ m_wv,
              const __hip_bfloat16* __restrict__ wimg, float* __restrict__ out) {
  extern __shared__ char smem[];
  const int tid  = threadIdx.x;
  const int lane = tid & 63;
  const int wave = tid >> 6;       // 0..3
  const int wm = wave >> 1;        // 0..1 : 32-row half of 64-h tile
  const int wn = wave & 1;         // 0..1 : 64-col half of 128-n tile

  // XCD swizzle (bijective: 4096 % 8 == 0), ht fastest -> 8 ht-sharers of one
  // X slab concurrent on one XCD's L2.
  const int wg  = blockIdx.x;
  const int swz = (wg & 7) * 512 + (wg >> 3);
  const int ht  = swz & 7;
  const int nt  = (swz >> 3) & 63;
  const int b   = swz >> 9;

  const int k0  = (tid & 15) << 2;   // 0..60  (4 k-rows per thread)
  const int n0s = (tid >> 4) << 3;   // 0..120 (8 n-cols per thread)

  const size_t batch_off = (size_t)b * HH * NN;
  const float* xm = m_wv + batch_off + (size_t)k0 * NN + nt * BN + n0s;
  const float* xe = e_wv + batch_off + (size_t)k0 * NN + nt * BN + n0s;
  const char*  wA = (const char*)wimg + (size_t)ht * NSTEPS * A_BYTES + tid * 16;

  f32x4 acc_r[2][4]  = {};
  f32x4 acc_z[2][4]  = {};
  f32x4 acc_in[2][4] = {};
  f32x4 acc_hn[2][4] = {};

  f32x4 cA[4], cB[4];   // transient f32 X (32 regs), loaded for step s+2
  uint2 pk[8];          // packed bf16 X for step s+1 (16 regs), crosses barrier

  // Precomputed within-buffer LDS read offsets.
  int aoff[2], boff[2];
#pragma unroll
  for (int kb2 = 0; kb2 < 2; ++kb2) {
    const int ke2 = kb2 * 64 + ((lane >> 4) << 4);
    const int sw  = (lane & 7) << 4;
    aoff[kb2] = (wm * 32 + (lane & 15)) * 128 + (ke2 ^ sw);
    boff[kb2] = A_BYTES + (wn * 64 + (lane & 15)) * 128 + (ke2 ^ sw);
  }

  auto issue_A = [&](int s, char* nb) {
    const char* gA = wA + (size_t)s * A_BYTES;
    char* lA = nb + tid * 16;
#pragma unroll
    for (int i = 0; i < 6; ++i)
      gload_lds16(gA + i * 4096, lA + i * 4096);
  };
  auto x_load = [&](const float* xs) {
#pragma unroll
    for (int i = 0; i < 4; ++i) {
      cA[i] = *(const f32x4*)(xs + (size_t)i * NN);
      cB[i] = *(const f32x4*)(xs + (size_t)i * NN + 4);
    }
  };
  auto x_cvt = [&]() {   // f32 (32 regs) -> packed bf16 (16 regs); waits on loads
#pragma unroll
    for (int j = 0; j < 4; ++j) {
      pk[j]     = make_uint2(cvt_pk_bf16(cA[0][j], cA[1][j]),
                             cvt_pk_bf16(cA[2][j], cA[3][j]));
      pk[j + 4] = make_uint2(cvt_pk_bf16(cB[0][j], cB[1][j]),
                             cvt_pk_bf16(cB[2][j], cB[3][j]));
    }
  };
  auto write_X = [&](char* nb) {   // pure LDS, no vmcnt dependency
    char* Bb = nb + A_BYTES;
#pragma unroll
    for (int j = 0; j < 8; ++j) {
      int off = (n0s + j) * 128 + ((k0 * 2) ^ (j << 4));   // (n&7)==j
      *(uint2*)(Bb + off) = pk[j];
    }
  };
  auto compute_kb2 = [&](const char* cb, int kb2, bool firstHalf) {
    short8 bfr[4];
#pragma unroll
    for (int ni = 0; ni < 4; ++ni)
      bfr[ni] = *(const short8*)(cb + boff[kb2] + ni * 2048);
    {  // gate r
      short8 a0 = *(const short8*)(cb + aoff[kb2]);
      short8 a1 = *(const short8*)(cb + aoff[kb2] + 2048);
#pragma unroll
      for (int ni = 0; ni < 4; ++ni) {
        acc_r[0][ni] = MFMA16(a0, bfr[ni], acc_r[0][ni]);
        acc_r[1][ni] = MFMA16(a1, bfr[ni], acc_r[1][ni]);
      }
    }
    {  // gate z
      short8 a0 = *(const short8*)(cb + aoff[kb2] + 8192);
      short8 a1 = *(const short8*)(cb + aoff[kb2] + 8192 + 2048);
#pragma unroll
      for (int ni = 0; ni < 4; ++ni) {
        acc_z[0][ni] = MFMA16(a0, bfr[ni], acc_z[0][ni]);
        acc_z[1][ni] = MFMA16(a1, bfr[ni], acc_z[1][ni]);
      }
    }
    {  // gate n -> acc_in (m-phase) / acc_hn (e-phase)
      short8 a0 = *(const short8*)(cb + aoff[kb2] + 16384);
      short8 a1 = *(const short8*)(cb + aoff[kb2] + 16384 + 2048);
      if (firstHalf) {
#pragma unroll
        for (int ni = 0; ni < 4; ++ni) {
          acc_in[0][ni] = MFMA16(a0, bfr[ni], acc_in[0][ni]);
          acc_in[1][ni] = MFMA16(a1, bfr[ni], acc_in[1][ni]);
        }
      } else {
#pragma unroll
        for (int ni = 0; ni < 4; ++ni) {
          acc_hn[0][ni] = MFMA16(a0, bfr[ni], acc_hn[0][ni]);
          acc_hn[1][ni] = MFMA16(a1, bfr[ni], acc_hn[1][ni]);
        }
      }
    }
  };

  // prologue: X(0) -> buf0, pk <- X(1), A(0) -> buf0
  issue_A(0, smem);
  x_load(xm);                       // X(0)
  x_cvt();
  write_X(smem);
  x_load(xm + (size_t)(64 * NN));   // X(1)
  x_cvt();                          // pk = X(1)
  __syncthreads();

#pragma unroll 1
  for (int s = 0; s < NSTEPS; ++s) {
    char* cb = smem + ((s & 1) ? BUF_BYTES : 0);
    char* nb = smem + ((s & 1) ? 0 : BUF_BYTES);
    const bool firstHalf = (s < 8);

    if (s < NSTEPS - 2) {           // issue X(s+2) loads first (oldest vm ops)
      const int t = s + 2;
      x_load((t < 8 ? xm : xe) + (size_t)(t & 7) * (64 * NN));
    }
    if (s < NSTEPS - 1) {
      write_X(nb);                  // X(s+1): packed regs -> LDS, no vm wait
      issue_A(s + 1, nb);
    }
    __builtin_amdgcn_s_setprio(1);
    compute_kb2(cb, 0, firstHalf);
    compute_kb2(cb, 1, firstHalf);
    __builtin_amdgcn_s_setprio(0);
    if (s < NSTEPS - 2) x_cvt();    // vm wait lands AFTER a full compute phase
    __syncthreads();
  }

  // epilogue: gates + blend (unchanged, verified R1-R5)
  const size_t obase = batch_off + (size_t)(ht * 64 + wm * 32) * NN + nt * BN + wn * 64;
  const float* ep = e_wv + obase;
  float* op = out + obase;
  const int rsub = (lane >> 4) << 2;
  const int csub = lane & 15;
#pragma unroll
  for (int mi = 0; mi < 2; ++mi)
#pragma unroll
    for (int ni = 0; ni < 4; ++ni) {
#pragma unroll
      for (int r = 0; r < 4; ++r) {
        size_t idx = (size_t)(mi * 16 + rsub + r) * NN + ni * 16 + csub;
        float pr  = acc_r[mi][ni][r];
        float pz  = acc_z[mi][ni][r];
        float vin = acc_in[mi][ni][r];
        float vhn = acc_hn[mi][ni][r];
        float rr  = 1.f / (1.f + __expf(-pr));
        float zz  = 1.f / (1.f + __expf(-pz));
        float ex  = __expf(2.f * (vin + rr * vhn));
        float nn2 = 1.f - 2.f / (ex + 1.f);      // tanh, inf-safe
        float ev  = ep[idx];
        op[idx] = (1.f - zz) * nn2 + zz * ev;
      }
    }
}

extern "C" void kernel_launch(void* const* d_in, const int* in_sizes, int n_in,
                              void* d_out, int out_size, void* d_ws, size_t ws_size,
                              hipStream_t stream) {
  const float* e_wv = (const float*)d_in[0];
  const float* m_wv = (const float*)d_in[1];
  const float* W_ih = (const float*)d_in[2];
  const float* W_hh = (const float*)d_in[3];
  float* out = (float*)d_out;
  __hip_bfloat16* wimg = (__hip_bfloat16*)d_ws;   // 3 MiB weight image

  (void)hipFuncSetAttribute((const void*)gru_main,
                            hipFuncAttributeMaxDynamicSharedMemorySize, LDS_TOTAL);

  prepack_w<<<(NBATCH * NSTEPS * 12288) / 256, 256, 0, stream>>>(W_ih, W_hh, wimg);
  gru_main<<<NBATCH * 8 * 64, THREADS, LDS_TOTAL, stream>>>(e_wv, m_wv, wimg, out);
}